// Round 6
// baseline (411.921 us; speedup 1.0000x reference)
//
#include <hip/hip_runtime.h>
#include <cstdint>
#include <cstddef>

// SplineNet: 2x SplineConv (K=3, K=5) + ELU, MLP head. N=100K, E=1.6M, D=64, C=16.
//
// R6: fused conv kernels. Per 64-node tile (512 threads):
//   phase 0: stage tile's own x rows into LDS As[.., K*64..]
//   phase 1: per-wave gather (8 nodes/wave, 4 edges in flight, hat weights,
//            fp32 acc, /deg) written into LDS As[.., 0..K*64) as fp16
//   phase 2: waves 0-3 MFMA 64x64 = [agg|x] @ Wt^T + bias, ELU
//   conv1: store h fp16. conv2: + fused MLP head (2 more MFMA stages through
//   LDS, fp16 weights) -> out fp32. agg/h2 never touch global memory.
// CSR build: R5 atomic-free partition sort; cvt/count/w-prep merged into one
// prep kernel. 8 dispatches total.
//
// ws: xh[N*64 h] | h[N*64 h] | packed[E int2] | staging[E int2] |
//     Wt1[64*256 h] | Wt2[64*384 h] | Wm1t[64*64 h] | Wm2t[16*64 h] |
//     counts[NBUCKET*128 u32] | partial[512] | rowptr[N+1]  ~= 52 MB.

#define D_FEAT 64
#define NB_MAX 1024
#define PART_B 128

typedef _Float16 half8v __attribute__((ext_vector_type(8)));
typedef _Float16 half4v __attribute__((ext_vector_type(4)));
typedef float f32x4 __attribute__((ext_vector_type(4)));

__device__ __forceinline__ float elu_f(float x) {
    return x > 0.f ? x : expm1f(x);
}

// ---------- merged prep: x->fp16 cvt | dst-bucket count | W transpose/cvt ----------

__global__ __launch_bounds__(256) void prep_k(
    const float* __restrict__ x, const int* __restrict__ edst,
    const float* __restrict__ W1, const float* __restrict__ root1,
    const float* __restrict__ W2, const float* __restrict__ root2,
    const float* __restrict__ Wm1, const float* __restrict__ Wm2,
    _Float16* __restrict__ xh, unsigned int* __restrict__ counts,
    _Float16* __restrict__ Wt1, _Float16* __restrict__ Wt2,
    _Float16* __restrict__ Wm1t, _Float16* __restrict__ Wm2t,
    int E, int chunk, int NBUCKET, int total8, int cvtB)
{
    __shared__ unsigned int hist[NB_MAX];
    int b = blockIdx.x, t = threadIdx.x;
    if (b < cvtB) {
        int i = b * 256 + t;
        if (i < total8) {
            const float4* src = (const float4*)(x + (size_t)i * 8);
            float4 v0 = src[0], v1 = src[1];
            half8v hv = { (_Float16)v0.x, (_Float16)v0.y, (_Float16)v0.z, (_Float16)v0.w,
                          (_Float16)v1.x, (_Float16)v1.y, (_Float16)v1.z, (_Float16)v1.w };
            ((half8v*)xh)[i] = hv;
        }
        return;
    }
    if (b < cvtB + PART_B) {
        int bb = b - cvtB;
        for (int i = t; i < NBUCKET; i += 256) hist[i] = 0u;
        __syncthreads();
        int e0 = bb * chunk;
        int e1 = e0 + chunk; if (e1 > E) e1 = E;
        for (int e = e0 + t; e < e1; e += 256)
            atomicAdd(&hist[edst[e] >> 7], 1u);
        __syncthreads();
        for (int i = t; i < NBUCKET; i += 256)
            counts[(size_t)i * PART_B + bb] = hist[i];
        return;
    }
    int i = (b - cvtB - PART_B) * 256 + t;
    if (i < 64 * 256) {
        int n = i >> 8, k = i & 255;
        float v = (k < 192) ? W1[k * 64 + n] : root1[(k - 192) * 64 + n];
        Wt1[n * 256 + k] = (_Float16)v;
    } else if (i < 64 * 256 + 64 * 384) {
        int j = i - 64 * 256;
        int n = j / 384, k = j % 384;
        float v = (k < 320) ? W2[k * 64 + n] : root2[(k - 320) * 64 + n];
        Wt2[n * 384 + k] = (_Float16)v;
    } else if (i < 64 * 256 + 64 * 384 + 64 * 64) {
        int j = i - 64 * 256 - 64 * 384;
        int n = j >> 6, k = j & 63;
        Wm1t[n * 64 + k] = (_Float16)Wm1[k * 64 + n];
    } else if (i < 64 * 256 + 64 * 384 + 64 * 64 + 16 * 64) {
        int j = i - 64 * 256 - 64 * 384 - 64 * 64;
        int n = j >> 6, k = j & 63;
        Wm2t[n * 64 + k] = (_Float16)Wm2[k * 16 + n];
    }
}

// ---------- flat multi-block exclusive scan over counts[L] ----------

__global__ __launch_bounds__(256) void psum_k(
    const unsigned int* __restrict__ data, unsigned int* __restrict__ partial, int L)
{
    __shared__ unsigned int wsum[4];
    int i = blockIdx.x * 256 + threadIdx.x;
    int lane = threadIdx.x & 63, wid = threadIdx.x >> 6;
    unsigned int v = (i < L) ? data[i] : 0u;
    #pragma unroll
    for (int off = 32; off; off >>= 1) v += __shfl_xor(v, off);
    if (lane == 0) wsum[wid] = v;
    __syncthreads();
    if (threadIdx.x == 0)
        partial[blockIdx.x] = wsum[0] + wsum[1] + wsum[2] + wsum[3];
}

__global__ __launch_bounds__(512) void pscan_k(
    unsigned int* __restrict__ partial, int nb)
{
    __shared__ unsigned int wsum[8];
    int t = threadIdx.x, lane = t & 63, wid = t >> 6;
    unsigned int v = (t < nb) ? partial[t] : 0u;
    unsigned int orig = v;
    #pragma unroll
    for (int off = 1; off < 64; off <<= 1) {
        unsigned int s = __shfl_up(v, off);
        if (lane >= off) v += s;
    }
    if (lane == 63) wsum[wid] = v;
    __syncthreads();
    unsigned int add = 0;
    for (int i = 0; i < wid; ++i) add += wsum[i];
    if (t < nb) partial[t] = v + add - orig;
}

__global__ __launch_bounds__(256) void pwrite_k(
    unsigned int* __restrict__ data, const unsigned int* __restrict__ partial, int L)
{
    __shared__ unsigned int wsum[4];
    int i = blockIdx.x * 256 + threadIdx.x;
    int lane = threadIdx.x & 63, wid = threadIdx.x >> 6;
    unsigned int v = (i < L) ? data[i] : 0u;
    unsigned int orig = v;
    #pragma unroll
    for (int off = 1; off < 64; off <<= 1) {
        unsigned int s = __shfl_up(v, off);
        if (lane >= off) v += s;
    }
    if (lane == 63) wsum[wid] = v;
    __syncthreads();
    unsigned int add = partial[blockIdx.x];
    for (int w = 0; w < wid; ++w) add += wsum[w];
    if (i < L) data[i] = add + v - orig;
}

// ---------- place + per-bucket sort (unchanged from R5) ----------

__global__ __launch_bounds__(256) void place_k(
    const int* __restrict__ esrc, const int* __restrict__ edst,
    const float* __restrict__ attr, const unsigned int* __restrict__ off,
    int2* __restrict__ staging, int E, int chunk, int NBUCKET)
{
    __shared__ unsigned int cur[NB_MAX];
    int t = threadIdx.x;
    for (int b = t; b < NBUCKET; b += 256)
        cur[b] = off[(size_t)b * PART_B + blockIdx.x];
    __syncthreads();
    int e0 = blockIdx.x * chunk;
    int e1 = e0 + chunk; if (e1 > E) e1 = E;
    for (int e = e0 + t; e < e1; e += 256) {
        int d = edst[e];
        unsigned int pos = atomicAdd(&cur[d >> 7], 1u);
        staging[pos] = make_int2(esrc[e] | ((d & 127) << 17), __float_as_int(attr[e]));
    }
}

__global__ __launch_bounds__(256) void binsort_k(
    const int2* __restrict__ staging, const unsigned int* __restrict__ off,
    unsigned int* __restrict__ rowptr, int2* __restrict__ packed,
    int N, int E, int NBUCKET)
{
    __shared__ unsigned int nh[128];
    __shared__ unsigned int cur[128];
    __shared__ unsigned int wtot[2];
    int bkt = blockIdx.x;
    int t = threadIdx.x;
    int node0 = bkt << 7;
    unsigned int start = off[(size_t)bkt * PART_B];
    unsigned int end = (bkt + 1 < NBUCKET) ? off[(size_t)(bkt + 1) * PART_B]
                                           : (unsigned int)E;
    if (t < 128) nh[t] = 0u;
    __syncthreads();
    for (unsigned int i = start + t; i < end; i += 256)
        atomicAdd(&nh[(staging[i].x >> 17) & 127], 1u);
    __syncthreads();
    if (t < 128) {
        int lane = t & 63;
        unsigned int v = nh[t], orig = v;
        #pragma unroll
        for (int o = 1; o < 64; o <<= 1) {
            unsigned int s = __shfl_up(v, o);
            if (lane >= o) v += s;
        }
        if (lane == 63) wtot[t >> 6] = v;
        nh[t] = v - orig;
    }
    __syncthreads();
    if (t < 128) {
        unsigned int add = (t >= 64) ? wtot[0] : 0u;
        unsigned int base = start + add + nh[t];
        cur[t] = base;
        int node = node0 + t;
        if (node < N) rowptr[node] = base;
    }
    if (bkt == NBUCKET - 1 && t == 0) rowptr[N] = (unsigned int)E;
    __syncthreads();
    for (unsigned int i = start + t; i < end; i += 256) {
        int2 r = staging[i];
        unsigned int pos = atomicAdd(&cur[(r.x >> 17) & 127], 1u);
        packed[pos] = make_int2(r.x & 0x1FFFF, r.y);
    }
}

// ---------- fused conv: gather->LDS, MFMA GEMM, (opt) fused MLP head ----------
// 64-node tile, 512 threads (8 waves). LDS As[64][Kd+8] fp16, Kd=K*64+64.
// phase1: wave w gathers nodes w*8..w*8+8 (4 edges in flight, lane=sub x half4-col).
// phase2: waves 0-3 do 16 rows each: [agg|x] @ Wt^T via mfma_f32_16x16x32_f16.
// Frag conv (R4/R5-verified): A[m=lane&15][k=q*8+j], B-frag reads Wt[n=lane&15][k],
// C/D: col=lane&15, row=q*4+reg.

template<int K, bool DO_MLP>
__global__ __launch_bounds__(512) void conv_fused(
    const _Float16* __restrict__ xin,
    const int2* __restrict__ packed,
    const unsigned int* __restrict__ rowptr,
    const _Float16* __restrict__ Wt,
    const float* __restrict__ bias,
    const _Float16* __restrict__ Wm1t,
    const float* __restrict__ bm1,
    const _Float16* __restrict__ Wm2t,
    const float* __restrict__ bm2,
    _Float16* __restrict__ outh,
    float* __restrict__ outf,
    int N)
{
    constexpr int Kd = K * 64 + 64;
    constexpr int S = Kd + 8;          // halves; 16B-aligned rows, bank step 4
    __shared__ _Float16 As[64 * S];    // K5: 50176 B, K3: 33792 B
    int t = threadIdx.x;
    int wv = t >> 6, lane = t & 63;
    int tile0 = blockIdx.x * 64;

    // phase 0: stage tile's x rows into As[:, K*64 .. Kd)
    {
        int row = t >> 3, col = (t & 7) * 8;
        int gr = tile0 + row; if (gr >= N) gr = N - 1;
        *(half8v*)&As[row * S + K * 64 + col] =
            *(const half8v*)(xin + (size_t)gr * D_FEAT + col);
    }

    // phase 1: gather into As[:, 0 .. K*64)
    {
        int sub = lane >> 4;
        int col = (lane & 15) << 2;
        for (int i = 0; i < 8; ++i) {
            int n = tile0 + wv * 8 + i;
            if (n >= N) break;
            unsigned int s0 = rowptr[n], s1 = rowptr[n + 1];
            float acc[K][4];
            #pragma unroll
            for (int k = 0; k < K; ++k)
                #pragma unroll
                for (int j = 0; j < 4; ++j) acc[k][j] = 0.f;
            for (unsigned int e = s0; e < s1; e += 4) {
                unsigned int ee = e + (unsigned int)sub;
                bool valid = ee < s1;
                int2 pe = packed[valid ? ee : s1 - 1];
                float v = __int_as_float(pe.y) * (float)(K - 1);
                v = valid ? v : -1e9f;              // poison -> all weights 0
                half4v hv = *(const half4v*)(xin + (size_t)pe.x * D_FEAT + col);
                float xv[4] = { (float)hv[0], (float)hv[1], (float)hv[2], (float)hv[3] };
                #pragma unroll
                for (int k = 0; k < K; ++k) {
                    float w = fmaxf(1.f - fabsf(v - (float)k), 0.f);
                    #pragma unroll
                    for (int j = 0; j < 4; ++j) acc[k][j] = fmaf(xv[j], w, acc[k][j]);
                }
            }
            float inv = 1.f / fmaxf((float)(s1 - s0), 1.f);
            #pragma unroll
            for (int k = 0; k < K; ++k) {
                float a[4];
                #pragma unroll
                for (int j = 0; j < 4; ++j) {
                    a[j] = acc[k][j];
                    a[j] += __shfl_xor(a[j], 16);
                    a[j] += __shfl_xor(a[j], 32);
                }
                if (sub == 0) {
                    half4v o = { (_Float16)(a[0] * inv), (_Float16)(a[1] * inv),
                                 (_Float16)(a[2] * inv), (_Float16)(a[3] * inv) };
                    *(half4v*)&As[(n - tile0) * S + k * 64 + col] = o;
                }
            }
        }
    }
    __syncthreads();

    // phase 2: [agg|x] @ Wt^T (waves 0-3, 16 rows each)
    int m16 = lane & 15, q = lane >> 4;
    f32x4 acc2[4];
    #pragma unroll
    for (int c = 0; c < 4; ++c) acc2[c] = (f32x4){0.f, 0.f, 0.f, 0.f};
    if (wv < 4) {
        int arow = wv * 16 + m16;
        for (int kk = 0; kk < Kd; kk += 32) {
            half8v af = *(const half8v*)&As[arow * S + kk + q * 8];
            #pragma unroll
            for (int c = 0; c < 4; ++c) {
                half8v bf = *(const half8v*)(Wt + (size_t)(c * 16 + m16) * Kd + kk + q * 8);
                acc2[c] = __builtin_amdgcn_mfma_f32_16x16x32_f16(af, bf, acc2[c], 0, 0, 0);
            }
        }
    }

    if (!DO_MLP) {
        if (wv < 4) {
            #pragma unroll
            for (int c = 0; c < 4; ++c) {
                int colg = c * 16 + m16;
                float bb = bias[colg];
                #pragma unroll
                for (int r = 0; r < 4; ++r) {
                    int rowg = tile0 + wv * 16 + q * 4 + r;
                    if (rowg < N)
                        outh[(size_t)rowg * D_FEAT + colg] = (_Float16)elu_f(acc2[c][r] + bb);
                }
            }
        }
        return;
    }

    // ---- fused MLP head (conv2 only); h2 tile stays in LDS ----
    constexpr int S2 = 72;
    _Float16* Hs  = As;             // [64][72]
    _Float16* Hs2 = As + 64 * S2;   // [64][72]
    __syncthreads();                // everyone done reading As
    if (wv < 4) {
        #pragma unroll
        for (int c = 0; c < 4; ++c) {
            int colg = c * 16 + m16;
            float bb = bias[colg];
            #pragma unroll
            for (int r = 0; r < 4; ++r)
                Hs[(wv * 16 + q * 4 + r) * S2 + colg] = (_Float16)elu_f(acc2[c][r] + bb);
        }
    }
    __syncthreads();
    f32x4 acc3[4];
    #pragma unroll
    for (int c = 0; c < 4; ++c) acc3[c] = (f32x4){0.f, 0.f, 0.f, 0.f};
    if (wv < 4) {
        #pragma unroll
        for (int kk = 0; kk < 64; kk += 32) {
            half8v af = *(const half8v*)&Hs[(wv * 16 + m16) * S2 + kk + q * 8];
            #pragma unroll
            for (int c = 0; c < 4; ++c) {
                half8v bf = *(const half8v*)(Wm1t + (size_t)(c * 16 + m16) * 64 + kk + q * 8);
                acc3[c] = __builtin_amdgcn_mfma_f32_16x16x32_f16(af, bf, acc3[c], 0, 0, 0);
            }
        }
    }
    __syncthreads();
    if (wv < 4) {
        #pragma unroll
        for (int c = 0; c < 4; ++c) {
            int colg = c * 16 + m16;
            float bb = bm1[colg];
            #pragma unroll
            for (int r = 0; r < 4; ++r)
                Hs2[(wv * 16 + q * 4 + r) * S2 + colg] =
                    (_Float16)fmaxf(acc3[c][r] + bb, 0.f);
        }
    }
    __syncthreads();
    if (wv < 4) {
        f32x4 acc4 = (f32x4){0.f, 0.f, 0.f, 0.f};
        #pragma unroll
        for (int kk = 0; kk < 64; kk += 32) {
            half8v af = *(const half8v*)&Hs2[(wv * 16 + m16) * S2 + kk + q * 8];
            half8v bf = *(const half8v*)(Wm2t + (size_t)m16 * 64 + kk + q * 8);
            acc4 = __builtin_amdgcn_mfma_f32_16x16x32_f16(af, bf, acc4, 0, 0, 0);
        }
        float bb = bm2[m16];
        #pragma unroll
        for (int r = 0; r < 4; ++r) {
            int rowg = tile0 + wv * 16 + q * 4 + r;
            if (rowg < N)
                outf[(size_t)rowg * 16 + m16] = fmaxf(acc4[r] + bb, 0.f);
        }
    }
}

extern "C" void kernel_launch(void* const* d_in, const int* in_sizes, int n_in,
                              void* d_out, int out_size, void* d_ws, size_t ws_size,
                              hipStream_t stream)
{
    const float* x     = (const float*)d_in[0];
    const int*   eidx  = (const int*)d_in[1];
    const float* attr  = (const float*)d_in[2];
    const float* W1    = (const float*)d_in[3];
    const float* root1 = (const float*)d_in[4];
    const float* b1    = (const float*)d_in[5];
    const float* W2    = (const float*)d_in[6];
    const float* root2 = (const float*)d_in[7];
    const float* b2    = (const float*)d_in[8];
    const float* Wm1   = (const float*)d_in[9];
    const float* bm1   = (const float*)d_in[10];
    const float* Wm2   = (const float*)d_in[11];
    const float* bm2   = (const float*)d_in[12];
    float* out = (float*)d_out;

    int N = in_sizes[0] / D_FEAT;
    int E = in_sizes[1] / 2;
    const int* esrc = eidx;
    const int* edst = eidx + E;
    int NBUCKET = (N + 127) >> 7;
    int chunk = (E + PART_B - 1) / PART_B;
    int L = NBUCKET * PART_B;
    int nbL = (L + 255) / 256;
    int total8 = N * D_FEAT / 8;
    int cvtB = (total8 + 255) / 256;
    int wElems = 64 * 256 + 64 * 384 + 64 * 64 + 16 * 64;
    int wB = (wElems + 255) / 256;

    _Float16* xh  = (_Float16*)d_ws;
    _Float16* h   = xh + (size_t)N * D_FEAT;
    int2* packed  = (int2*)(h + (size_t)N * D_FEAT);
    int2* staging = packed + E;
    _Float16* Wt1 = (_Float16*)(staging + E);
    _Float16* Wt2 = Wt1 + 64 * 256;
    _Float16* Wm1t = Wt2 + 64 * 384;
    _Float16* Wm2t = Wm1t + 64 * 64;
    unsigned int* counts  = (unsigned int*)(Wm2t + 16 * 64);
    unsigned int* partial = counts + L;
    unsigned int* rowptr  = partial + 512;

    dim3 blk(256);
    dim3 grid_t((N + 63) / 64);

    // prep: cvt x | bucket count | W transposes (one dispatch)
    prep_k<<<dim3(cvtB + PART_B + wB), blk, 0, stream>>>(
        x, edst, W1, root1, W2, root2, Wm1, Wm2,
        xh, counts, Wt1, Wt2, Wm1t, Wm2t, E, chunk, NBUCKET, total8, cvtB);

    // scan + place + per-bucket sort
    psum_k<<<dim3(nbL), blk, 0, stream>>>(counts, partial, L);
    pscan_k<<<1, 512, 0, stream>>>(partial, nbL);
    pwrite_k<<<dim3(nbL), blk, 0, stream>>>(counts, partial, L);
    place_k<<<dim3(PART_B), blk, 0, stream>>>(esrc, edst, attr, counts, staging, E, chunk, NBUCKET);
    binsort_k<<<dim3(NBUCKET), blk, 0, stream>>>(staging, counts, rowptr, packed, N, E, NBUCKET);

    // fused convs
    conv_fused<3, false><<<grid_t, dim3(512), 0, stream>>>(
        xh, packed, rowptr, Wt1, b1, nullptr, nullptr, nullptr, nullptr, h, nullptr, N);
    conv_fused<5, true><<<grid_t, dim3(512), 0, stream>>>(
        h, packed, rowptr, Wt2, b2, Wm1t, bm1, Wm2t, bm2, nullptr, out, N);
}

// Round 7
// 371.974 us; speedup vs baseline: 1.1074x; 1.1074x over previous
//
#include <hip/hip_runtime.h>
#include <cstdint>
#include <cstddef>

// SplineNet: 2x SplineConv (K=3, K=5) + ELU, MLP head. N=100K, E=1.6M, D=64, C=16.
//
// R7 (R6 fusion reverted — it cost occupancy):
//  - binsort sorts each node's edges by attr quartile q=floor(4p) (512 LDS
//    counters) and emits slotptr[N*4+1]. One sort serves both K (monotone).
//  - gather loops the 4 buckets with COMPILE-TIME slot indices: 8 FMAs +
//    3 weight ops per edge instead of 4K FMAs + 3K hat ops (R5: 46 VALU/edge).
//  - MLP head fused into gemm<5> epilogue (2 MFMA stages via LDS, per-wave
//    self-contained rows); mlp_tile and the h2 round-trip deleted.
//
// ws: agg[N*320 h] 64MB | xh[N*64 h] | h[N*64 h] | packed[E int2] |
//     staging[E int2] | Wt1 | Wt2 | Wm1t | Wm2t | counts | partial |
//     slotptr[N*4+1]  ~= 118 MB.

#define D_FEAT 64
#define AS_STRIDE 40
#define NB_MAX 1024
#define PART_B 128

typedef _Float16 half8v __attribute__((ext_vector_type(8)));
typedef _Float16 half4v __attribute__((ext_vector_type(4)));
typedef float f32x4 __attribute__((ext_vector_type(4)));

__device__ __forceinline__ float elu_f(float x) {
    return x > 0.f ? x : expm1f(x);
}

// ---------- merged prep: x->fp16 | dst-bucket count | W transposes ----------

__global__ __launch_bounds__(256) void prep_k(
    const float* __restrict__ x, const int* __restrict__ edst,
    const float* __restrict__ W1, const float* __restrict__ root1,
    const float* __restrict__ W2, const float* __restrict__ root2,
    const float* __restrict__ Wm1, const float* __restrict__ Wm2,
    _Float16* __restrict__ xh, unsigned int* __restrict__ counts,
    _Float16* __restrict__ Wt1, _Float16* __restrict__ Wt2,
    _Float16* __restrict__ Wm1t, _Float16* __restrict__ Wm2t,
    int E, int chunk, int NBUCKET, int total8, int cvtB)
{
    __shared__ unsigned int hist[NB_MAX];
    int b = blockIdx.x, t = threadIdx.x;
    if (b < cvtB) {
        int i = b * 256 + t;
        if (i < total8) {
            const float4* src = (const float4*)(x + (size_t)i * 8);
            float4 v0 = src[0], v1 = src[1];
            half8v hv = { (_Float16)v0.x, (_Float16)v0.y, (_Float16)v0.z, (_Float16)v0.w,
                          (_Float16)v1.x, (_Float16)v1.y, (_Float16)v1.z, (_Float16)v1.w };
            ((half8v*)xh)[i] = hv;
        }
        return;
    }
    if (b < cvtB + PART_B) {
        int bb = b - cvtB;
        for (int i = t; i < NBUCKET; i += 256) hist[i] = 0u;
        __syncthreads();
        int e0 = bb * chunk;
        int e1 = e0 + chunk; if (e1 > E) e1 = E;
        for (int e = e0 + t; e < e1; e += 256)
            atomicAdd(&hist[edst[e] >> 7], 1u);
        __syncthreads();
        for (int i = t; i < NBUCKET; i += 256)
            counts[(size_t)i * PART_B + bb] = hist[i];
        return;
    }
    int i = (b - cvtB - PART_B) * 256 + t;
    if (i < 64 * 256) {
        int n = i >> 8, k = i & 255;
        float v = (k < 192) ? W1[k * 64 + n] : root1[(k - 192) * 64 + n];
        Wt1[n * 256 + k] = (_Float16)v;
    } else if (i < 64 * 256 + 64 * 384) {
        int j = i - 64 * 256;
        int n = j / 384, k = j % 384;
        float v = (k < 320) ? W2[k * 64 + n] : root2[(k - 320) * 64 + n];
        Wt2[n * 384 + k] = (_Float16)v;
    } else if (i < 64 * 256 + 64 * 384 + 64 * 64) {
        int j = i - 64 * 256 - 64 * 384;
        int n = j >> 6, k = j & 63;
        Wm1t[n * 64 + k] = (_Float16)Wm1[k * 64 + n];
    } else if (i < 64 * 256 + 64 * 384 + 64 * 64 + 16 * 64) {
        int j = i - 64 * 256 - 64 * 384 - 64 * 64;
        int n = j >> 6, k = j & 63;
        Wm2t[n * 64 + k] = (_Float16)Wm2[k * 16 + n];
    }
}

// ---------- flat multi-block exclusive scan over counts[L] ----------

__global__ __launch_bounds__(256) void psum_k(
    const unsigned int* __restrict__ data, unsigned int* __restrict__ partial, int L)
{
    __shared__ unsigned int wsum[4];
    int i = blockIdx.x * 256 + threadIdx.x;
    int lane = threadIdx.x & 63, wid = threadIdx.x >> 6;
    unsigned int v = (i < L) ? data[i] : 0u;
    #pragma unroll
    for (int off = 32; off; off >>= 1) v += __shfl_xor(v, off);
    if (lane == 0) wsum[wid] = v;
    __syncthreads();
    if (threadIdx.x == 0)
        partial[blockIdx.x] = wsum[0] + wsum[1] + wsum[2] + wsum[3];
}

__global__ __launch_bounds__(512) void pscan_k(
    unsigned int* __restrict__ partial, int nb)
{
    __shared__ unsigned int wsum[8];
    int t = threadIdx.x, lane = t & 63, wid = t >> 6;
    unsigned int v = (t < nb) ? partial[t] : 0u;
    unsigned int orig = v;
    #pragma unroll
    for (int off = 1; off < 64; off <<= 1) {
        unsigned int s = __shfl_up(v, off);
        if (lane >= off) v += s;
    }
    if (lane == 63) wsum[wid] = v;
    __syncthreads();
    unsigned int add = 0;
    for (int i = 0; i < wid; ++i) add += wsum[i];
    if (t < nb) partial[t] = v + add - orig;
}

__global__ __launch_bounds__(256) void pwrite_k(
    unsigned int* __restrict__ data, const unsigned int* __restrict__ partial, int L)
{
    __shared__ unsigned int wsum[4];
    int i = blockIdx.x * 256 + threadIdx.x;
    int lane = threadIdx.x & 63, wid = threadIdx.x >> 6;
    unsigned int v = (i < L) ? data[i] : 0u;
    unsigned int orig = v;
    #pragma unroll
    for (int off = 1; off < 64; off <<= 1) {
        unsigned int s = __shfl_up(v, off);
        if (lane >= off) v += s;
    }
    if (lane == 63) wsum[wid] = v;
    __syncthreads();
    unsigned int add = partial[blockIdx.x];
    for (int w = 0; w < wid; ++w) add += wsum[w];
    if (i < L) data[i] = add + v - orig;
}

// ---------- place into bucket-grouped staging (LDS cursors) ----------

__global__ __launch_bounds__(256) void place_k(
    const int* __restrict__ esrc, const int* __restrict__ edst,
    const float* __restrict__ attr, const unsigned int* __restrict__ off,
    int2* __restrict__ staging, int E, int chunk, int NBUCKET)
{
    __shared__ unsigned int cur[NB_MAX];
    int t = threadIdx.x;
    for (int b = t; b < NBUCKET; b += 256)
        cur[b] = off[(size_t)b * PART_B + blockIdx.x];
    __syncthreads();
    int e0 = blockIdx.x * chunk;
    int e1 = e0 + chunk; if (e1 > E) e1 = E;
    for (int e = e0 + t; e < e1; e += 256) {
        int d = edst[e];
        unsigned int pos = atomicAdd(&cur[d >> 7], 1u);
        staging[pos] = make_int2(esrc[e] | ((d & 127) << 17), __float_as_int(attr[e]));
    }
}

// ---------- per-bucket sort by (node, quartile); emits slotptr ----------

__global__ __launch_bounds__(256) void binsort_k(
    const int2* __restrict__ staging, const unsigned int* __restrict__ off,
    unsigned int* __restrict__ slotptr, int2* __restrict__ packed,
    int N, int E, int NBUCKET)
{
    __shared__ unsigned int nh[512];
    __shared__ unsigned int curb[512];
    __shared__ unsigned int wsum[4];
    int bkt = blockIdx.x, t = threadIdx.x;
    int node0 = bkt << 7;
    unsigned int start = off[(size_t)bkt * PART_B];
    unsigned int end = (bkt + 1 < NBUCKET) ? off[(size_t)(bkt + 1) * PART_B]
                                           : (unsigned int)E;
    nh[t] = 0u; nh[t + 256] = 0u;
    __syncthreads();
    for (unsigned int i = start + t; i < end; i += 256) {
        int2 r = staging[i];
        float p = __int_as_float(r.y);
        int q = (int)(p * 4.0f); q = q > 3 ? 3 : q;
        atomicAdd(&nh[(((r.x >> 17) & 127) << 2) | q], 1u);
    }
    __syncthreads();
    int lane = t & 63, wid = t >> 6;
    unsigned int v0 = nh[2 * t], v1 = nh[2 * t + 1];
    unsigned int pair = v0 + v1, inc = pair;
    #pragma unroll
    for (int o = 1; o < 64; o <<= 1) {
        unsigned int s = __shfl_up(inc, o);
        if (lane >= o) inc += s;
    }
    if (lane == 63) wsum[wid] = inc;
    __syncthreads();
    unsigned int wo = 0;
    for (int i = 0; i < wid; ++i) wo += wsum[i];
    unsigned int excl = wo + inc - pair;
    unsigned int b0 = start + excl, b1 = b0 + v0;
    curb[2 * t] = b0; curb[2 * t + 1] = b1;
    int j0 = 2 * t, j1 = 2 * t + 1;
    if (node0 + (j0 >> 2) < N) slotptr[(size_t)node0 * 4 + j0] = b0;
    if (node0 + (j1 >> 2) < N) slotptr[(size_t)node0 * 4 + j1] = b1;
    if (bkt == NBUCKET - 1 && t == 0) slotptr[(size_t)N * 4] = (unsigned int)E;
    __syncthreads();
    for (unsigned int i = start + t; i < end; i += 256) {
        int2 r = staging[i];
        float p = __int_as_float(r.y);
        int q = (int)(p * 4.0f); q = q > 3 ? 3 : q;
        unsigned int pos = atomicAdd(&curb[(((r.x >> 17) & 127) << 2) | q], 1u);
        packed[pos] = make_int2(r.x & 0x1FFFF, r.y);
    }
}

// ---------- gather with quartile-run slot indexing ----------
// wave = node; lane = (edge-slot sub 0..3) x (16 half4 cols). For each
// quartile bucket q (compile-time loop) only slots k0, k0+1 are touched:
// 8 FMAs + 3 weight ops per edge.

template<int K>
__global__ __launch_bounds__(256) void gather_k(
    const _Float16* __restrict__ xin,
    const int2* __restrict__ packed,
    const unsigned int* __restrict__ slotptr,
    _Float16* __restrict__ agg, int N)
{
    int n = blockIdx.x * 4 + (threadIdx.x >> 6);
    int lane = threadIdx.x & 63;
    if (n >= N) return;
    int sub = lane >> 4;
    int col = (lane & 15) << 2;
    unsigned int sp[5];
    #pragma unroll
    for (int q = 0; q < 5; ++q) sp[q] = slotptr[(size_t)n * 4 + q];
    float acc[K][4];
    #pragma unroll
    for (int k = 0; k < K; ++k)
        #pragma unroll
        for (int j = 0; j < 4; ++j) acc[k][j] = 0.f;
    #pragma unroll
    for (int q = 0; q < 4; ++q) {
        const int k0 = (K == 5) ? q : (q >> 1);
        unsigned int s0 = sp[q], s1 = sp[q + 1];
        for (unsigned int e = s0; e < s1; e += 4) {
            unsigned int ee = e + (unsigned int)sub;
            bool valid = ee < s1;
            int2 pe = packed[valid ? ee : s1 - 1];
            float f = __int_as_float(pe.y) * 4.0f;
            float frac = (K == 5) ? (f - (float)q) : (f * 0.5f - (float)k0);
            float w1 = valid ? frac : 0.f;
            float w0 = valid ? 1.f - frac : 0.f;
            half4v hv = *(const half4v*)(xin + (size_t)pe.x * D_FEAT + col);
            #pragma unroll
            for (int j = 0; j < 4; ++j) {
                float xv = (float)hv[j];
                acc[k0][j]     = fmaf(xv, w0, acc[k0][j]);
                acc[k0 + 1][j] = fmaf(xv, w1, acc[k0 + 1][j]);
            }
        }
    }
    float inv = 1.f / fmaxf((float)(sp[4] - sp[0]), 1.f);
    #pragma unroll
    for (int k = 0; k < K; ++k) {
        float a[4];
        #pragma unroll
        for (int j = 0; j < 4; ++j) {
            a[j] = acc[k][j];
            a[j] += __shfl_xor(a[j], 16);
            a[j] += __shfl_xor(a[j], 32);
        }
        if (sub == 0) {
            half4v o = { (_Float16)(a[0] * inv), (_Float16)(a[1] * inv),
                         (_Float16)(a[2] * inv), (_Float16)(a[3] * inv) };
            *(half4v*)(agg + ((size_t)n * K + k) * D_FEAT + col) = o;
        }
    }
}

// ---------- MFMA GEMM (+ optional fused MLP head) ----------
// 128x64 tile / 256 threads; wave w = rows w*32..w*32+31.
// Frags (R4/R5-verified): A[m=lane&15][k=q*8+j], B from Wt[n=lane&15][k],
// C/D col=lane&15, row=q*4+reg.
// DO_MLP: h2 tile -> LDS (per-wave rows), 2 more MFMA stages, fp32 out.

template<int K, bool DO_MLP>
__global__ __launch_bounds__(256) void gemm_mfma(
    const _Float16* __restrict__ A,
    const _Float16* __restrict__ X,
    const _Float16* __restrict__ Wt,
    const float* __restrict__ bias,
    const _Float16* __restrict__ Wm1t,
    const float* __restrict__ bm1,
    const _Float16* __restrict__ Wm2t,
    const float* __restrict__ bm2,
    _Float16* __restrict__ outh,
    float* __restrict__ outf,
    int N)
{
    constexpr int lenA = K * 64;
    constexpr int Kd = lenA + D_FEAT;
    constexpr int SMEM_H = DO_MLP ? (128 * 72 * 2) : (128 * AS_STRIDE + 64 * AS_STRIDE);
    __shared__ _Float16 smem[SMEM_H];
    _Float16* As = smem;
    _Float16* Bs = smem + 128 * AS_STRIDE;

    int t = threadIdx.x;
    int row0 = blockIdx.x * 128;
    int w = t >> 6, lane = t & 63;
    int m16 = lane & 15, q = lane >> 4;

    f32x4 acc[2][4];
    #pragma unroll
    for (int rf = 0; rf < 2; ++rf)
        #pragma unroll
        for (int c = 0; c < 4; ++c) acc[rf][c] = (f32x4){0.f, 0.f, 0.f, 0.f};

    int srow = t >> 1;
    int skh  = (t & 1) * 16;
    int bn   = t >> 2;
    int bkq  = (t & 3) * 8;

    int grow = row0 + srow; if (grow >= N) grow = N - 1;
    const _Float16* arowA = A + (size_t)grow * lenA;
    const _Float16* arowX = X + (size_t)grow * D_FEAT;

    for (int kk = 0; kk < Kd; kk += 32) {
        const _Float16* src = (kk < lenA) ? (arowA + kk + skh)
                                          : (arowX + (kk - lenA) + skh);
        half8v a0 = *(const half8v*)(src);
        half8v a1 = *(const half8v*)(src + 8);
        half8v b0 = *(const half8v*)(Wt + (size_t)bn * Kd + kk + bkq);
        __syncthreads();
        *(half8v*)(&As[srow * AS_STRIDE + skh]) = a0;
        *(half8v*)(&As[srow * AS_STRIDE + skh + 8]) = a1;
        *(half8v*)(&Bs[bn * AS_STRIDE + bkq]) = b0;
        __syncthreads();
        half8v af0 = *(const half8v*)(&As[(w * 32 + m16) * AS_STRIDE + q * 8]);
        half8v af1 = *(const half8v*)(&As[(w * 32 + 16 + m16) * AS_STRIDE + q * 8]);
        #pragma unroll
        for (int c = 0; c < 4; ++c) {
            half8v bf = *(const half8v*)(&Bs[(c * 16 + m16) * AS_STRIDE + q * 8]);
            acc[0][c] = __builtin_amdgcn_mfma_f32_16x16x32_f16(af0, bf, acc[0][c], 0, 0, 0);
            acc[1][c] = __builtin_amdgcn_mfma_f32_16x16x32_f16(af1, bf, acc[1][c], 0, 0, 0);
        }
    }

    if (!DO_MLP) {
        #pragma unroll
        for (int rf = 0; rf < 2; ++rf)
            #pragma unroll
            for (int c = 0; c < 4; ++c) {
                int colg = c * 16 + m16;
                float bb = bias[colg];
                #pragma unroll
                for (int r = 0; r < 4; ++r) {
                    int rowg = row0 + w * 32 + rf * 16 + q * 4 + r;
                    if (rowg < N)
                        outh[(size_t)rowg * D_FEAT + colg] = (_Float16)elu_f(acc[rf][c][r] + bb);
                }
            }
        return;
    }

    // fused MLP head: per-wave self-contained rows (w*32..w*32+31)
    _Float16* Hs  = smem;               // [128][72]
    _Float16* Hs2 = smem + 128 * 72;    // [128][72]
    __syncthreads();                    // done with As/Bs
    #pragma unroll
    for (int rf = 0; rf < 2; ++rf)
        #pragma unroll
        for (int c = 0; c < 4; ++c) {
            int colg = c * 16 + m16;
            float bb = bias[colg];
            #pragma unroll
            for (int r = 0; r < 4; ++r)
                Hs[(w * 32 + rf * 16 + q * 4 + r) * 72 + colg] =
                    (_Float16)elu_f(acc[rf][c][r] + bb);
        }

    f32x4 acc3[2][4];
    #pragma unroll
    for (int rf = 0; rf < 2; ++rf)
        #pragma unroll
        for (int c = 0; c < 4; ++c) acc3[rf][c] = (f32x4){0.f, 0.f, 0.f, 0.f};
    #pragma unroll
    for (int kk = 0; kk < 64; kk += 32) {
        half8v af0 = *(const half8v*)(&Hs[(w * 32 + m16) * 72 + kk + q * 8]);
        half8v af1 = *(const half8v*)(&Hs[(w * 32 + 16 + m16) * 72 + kk + q * 8]);
        #pragma unroll
        for (int c = 0; c < 4; ++c) {
            half8v bf = *(const half8v*)(Wm1t + (size_t)(c * 16 + m16) * 64 + kk + q * 8);
            acc3[0][c] = __builtin_amdgcn_mfma_f32_16x16x32_f16(af0, bf, acc3[0][c], 0, 0, 0);
            acc3[1][c] = __builtin_amdgcn_mfma_f32_16x16x32_f16(af1, bf, acc3[1][c], 0, 0, 0);
        }
    }
    #pragma unroll
    for (int rf = 0; rf < 2; ++rf)
        #pragma unroll
        for (int c = 0; c < 4; ++c) {
            int colg = c * 16 + m16;
            float bb = bm1[colg];
            #pragma unroll
            for (int r = 0; r < 4; ++r)
                Hs2[(w * 32 + rf * 16 + q * 4 + r) * 72 + colg] =
                    (_Float16)fmaxf(acc3[rf][c][r] + bb, 0.f);
        }

    f32x4 acc4[2];
    acc4[0] = (f32x4){0.f, 0.f, 0.f, 0.f};
    acc4[1] = (f32x4){0.f, 0.f, 0.f, 0.f};
    #pragma unroll
    for (int kk = 0; kk < 64; kk += 32) {
        half8v af0 = *(const half8v*)(&Hs2[(w * 32 + m16) * 72 + kk + q * 8]);
        half8v af1 = *(const half8v*)(&Hs2[(w * 32 + 16 + m16) * 72 + kk + q * 8]);
        half8v bf = *(const half8v*)(Wm2t + (size_t)m16 * 64 + kk + q * 8);
        acc4[0] = __builtin_amdgcn_mfma_f32_16x16x32_f16(af0, bf, acc4[0], 0, 0, 0);
        acc4[1] = __builtin_amdgcn_mfma_f32_16x16x32_f16(af1, bf, acc4[1], 0, 0, 0);
    }
    float bb2 = bm2[m16];
    #pragma unroll
    for (int rf = 0; rf < 2; ++rf)
        #pragma unroll
        for (int r = 0; r < 4; ++r) {
            int rowg = row0 + w * 32 + rf * 16 + q * 4 + r;
            if (rowg < N)
                outf[(size_t)rowg * 16 + m16] = fmaxf(acc4[rf][r] + bb2, 0.f);
        }
}

extern "C" void kernel_launch(void* const* d_in, const int* in_sizes, int n_in,
                              void* d_out, int out_size, void* d_ws, size_t ws_size,
                              hipStream_t stream)
{
    const float* x     = (const float*)d_in[0];
    const int*   eidx  = (const int*)d_in[1];
    const float* attr  = (const float*)d_in[2];
    const float* W1    = (const float*)d_in[3];
    const float* root1 = (const float*)d_in[4];
    const float* b1    = (const float*)d_in[5];
    const float* W2    = (const float*)d_in[6];
    const float* root2 = (const float*)d_in[7];
    const float* b2    = (const float*)d_in[8];
    const float* Wm1   = (const float*)d_in[9];
    const float* bm1   = (const float*)d_in[10];
    const float* Wm2   = (const float*)d_in[11];
    const float* bm2   = (const float*)d_in[12];
    float* out = (float*)d_out;

    int N = in_sizes[0] / D_FEAT;
    int E = in_sizes[1] / 2;
    const int* esrc = eidx;
    const int* edst = eidx + E;
    int NBUCKET = (N + 127) >> 7;
    int chunk = (E + PART_B - 1) / PART_B;
    int L = NBUCKET * PART_B;
    int nbL = (L + 255) / 256;
    int total8 = N * D_FEAT / 8;
    int cvtB = (total8 + 255) / 256;
    int wElems = 64 * 256 + 64 * 384 + 64 * 64 + 16 * 64;
    int wB = (wElems + 255) / 256;

    _Float16* agg = (_Float16*)d_ws;
    _Float16* xh  = agg + (size_t)N * 5 * D_FEAT;
    _Float16* h   = xh + (size_t)N * D_FEAT;
    int2* packed  = (int2*)(h + (size_t)N * D_FEAT);
    int2* staging = packed + E;
    _Float16* Wt1 = (_Float16*)(staging + E);
    _Float16* Wt2 = Wt1 + 64 * 256;
    _Float16* Wm1t = Wt2 + 64 * 384;
    _Float16* Wm2t = Wm1t + 64 * 64;
    unsigned int* counts  = (unsigned int*)(Wm2t + 16 * 64);
    unsigned int* partial = counts + L;
    unsigned int* slotptr = partial + 512;

    dim3 blk(256);
    dim3 grid_w((N + 3) / 4);
    dim3 grid_g128((N + 127) / 128);

    prep_k<<<dim3(cvtB + PART_B + wB), blk, 0, stream>>>(
        x, edst, W1, root1, W2, root2, Wm1, Wm2,
        xh, counts, Wt1, Wt2, Wm1t, Wm2t, E, chunk, NBUCKET, total8, cvtB);

    psum_k<<<dim3(nbL), blk, 0, stream>>>(counts, partial, L);
    pscan_k<<<1, 512, 0, stream>>>(partial, nbL);
    pwrite_k<<<dim3(nbL), blk, 0, stream>>>(counts, partial, L);
    place_k<<<dim3(PART_B), blk, 0, stream>>>(esrc, edst, attr, counts, staging, E, chunk, NBUCKET);
    binsort_k<<<dim3(NBUCKET), blk, 0, stream>>>(staging, counts, slotptr, packed, N, E, NBUCKET);

    // conv1: K=3
    gather_k<3><<<grid_w, blk, 0, stream>>>(xh, packed, slotptr, agg, N);
    gemm_mfma<3, false><<<grid_g128, blk, 0, stream>>>(
        agg, xh, Wt1, b1, nullptr, nullptr, nullptr, nullptr, h, nullptr, N);

    // conv2: K=5 + fused MLP head
    gather_k<5><<<grid_w, blk, 0, stream>>>(h, packed, slotptr, agg, N);
    gemm_mfma<5, true><<<grid_g128, blk, 0, stream>>>(
        agg, h, Wt2, b2, Wm1t, bm1, Wm2t, bm2, nullptr, out, N);
}

// Round 8
// 334.194 us; speedup vs baseline: 1.2326x; 1.1130x over previous
//
#include <hip/hip_runtime.h>
#include <cstdint>
#include <cstddef>

// SplineNet: 2x SplineConv (K=3, K=5) + ELU, MLP head. N=100K, E=1.6M, D=64, C=16.
//
// R8: gather rebuilt as phase-paired dual-stream quartile loop:
//   phase 0 runs buckets {0,2} concurrently, phase 1 runs {1,3}. Slot pairs
//   are disjoint (K=5) or share one acc (K=3, serialized FMA — correct).
//   2 packed-loads + 2 row-loads in flight/iter, compile-time slot indices,
//   fp32 acc[K][4] (20 VGPR). ~3.1 loop trips/node vs R7's 5.2.
// Rest unchanged from R7 (quartile binsort -> slotptr; MFMA GEMMs; MLP head
// fused into gemm<5> epilogue; atomic-free partition-sort CSR build).
//
// ws: agg[N*320 h] 64MB | xh[N*64 h] | h[N*64 h] | packed[E int2] |
//     staging[E int2] | Wt1 | Wt2 | Wm1t | Wm2t | counts | partial |
//     slotptr[N*4+1]  ~= 118 MB.

#define D_FEAT 64
#define AS_STRIDE 40
#define NB_MAX 1024
#define PART_B 128

typedef _Float16 half8v __attribute__((ext_vector_type(8)));
typedef _Float16 half4v __attribute__((ext_vector_type(4)));
typedef float f32x4 __attribute__((ext_vector_type(4)));

__device__ __forceinline__ float elu_f(float x) {
    return x > 0.f ? x : expm1f(x);
}

// ---------- merged prep: x->fp16 | dst-bucket count | W transposes ----------

__global__ __launch_bounds__(256) void prep_k(
    const float* __restrict__ x, const int* __restrict__ edst,
    const float* __restrict__ W1, const float* __restrict__ root1,
    const float* __restrict__ W2, const float* __restrict__ root2,
    const float* __restrict__ Wm1, const float* __restrict__ Wm2,
    _Float16* __restrict__ xh, unsigned int* __restrict__ counts,
    _Float16* __restrict__ Wt1, _Float16* __restrict__ Wt2,
    _Float16* __restrict__ Wm1t, _Float16* __restrict__ Wm2t,
    int E, int chunk, int NBUCKET, int total8, int cvtB)
{
    __shared__ unsigned int hist[NB_MAX];
    int b = blockIdx.x, t = threadIdx.x;
    if (b < cvtB) {
        int i = b * 256 + t;
        if (i < total8) {
            const float4* src = (const float4*)(x + (size_t)i * 8);
            float4 v0 = src[0], v1 = src[1];
            half8v hv = { (_Float16)v0.x, (_Float16)v0.y, (_Float16)v0.z, (_Float16)v0.w,
                          (_Float16)v1.x, (_Float16)v1.y, (_Float16)v1.z, (_Float16)v1.w };
            ((half8v*)xh)[i] = hv;
        }
        return;
    }
    if (b < cvtB + PART_B) {
        int bb = b - cvtB;
        for (int i = t; i < NBUCKET; i += 256) hist[i] = 0u;
        __syncthreads();
        int e0 = bb * chunk;
        int e1 = e0 + chunk; if (e1 > E) e1 = E;
        for (int e = e0 + t; e < e1; e += 256)
            atomicAdd(&hist[edst[e] >> 7], 1u);
        __syncthreads();
        for (int i = t; i < NBUCKET; i += 256)
            counts[(size_t)i * PART_B + bb] = hist[i];
        return;
    }
    int i = (b - cvtB - PART_B) * 256 + t;
    if (i < 64 * 256) {
        int n = i >> 8, k = i & 255;
        float v = (k < 192) ? W1[k * 64 + n] : root1[(k - 192) * 64 + n];
        Wt1[n * 256 + k] = (_Float16)v;
    } else if (i < 64 * 256 + 64 * 384) {
        int j = i - 64 * 256;
        int n = j / 384, k = j % 384;
        float v = (k < 320) ? W2[k * 64 + n] : root2[(k - 320) * 64 + n];
        Wt2[n * 384 + k] = (_Float16)v;
    } else if (i < 64 * 256 + 64 * 384 + 64 * 64) {
        int j = i - 64 * 256 - 64 * 384;
        int n = j >> 6, k = j & 63;
        Wm1t[n * 64 + k] = (_Float16)Wm1[k * 64 + n];
    } else if (i < 64 * 256 + 64 * 384 + 64 * 64 + 16 * 64) {
        int j = i - 64 * 256 - 64 * 384 - 64 * 64;
        int n = j >> 6, k = j & 63;
        Wm2t[n * 64 + k] = (_Float16)Wm2[k * 16 + n];
    }
}

// ---------- flat multi-block exclusive scan over counts[L] ----------

__global__ __launch_bounds__(256) void psum_k(
    const unsigned int* __restrict__ data, unsigned int* __restrict__ partial, int L)
{
    __shared__ unsigned int wsum[4];
    int i = blockIdx.x * 256 + threadIdx.x;
    int lane = threadIdx.x & 63, wid = threadIdx.x >> 6;
    unsigned int v = (i < L) ? data[i] : 0u;
    #pragma unroll
    for (int off = 32; off; off >>= 1) v += __shfl_xor(v, off);
    if (lane == 0) wsum[wid] = v;
    __syncthreads();
    if (threadIdx.x == 0)
        partial[blockIdx.x] = wsum[0] + wsum[1] + wsum[2] + wsum[3];
}

__global__ __launch_bounds__(512) void pscan_k(
    unsigned int* __restrict__ partial, int nb)
{
    __shared__ unsigned int wsum[8];
    int t = threadIdx.x, lane = t & 63, wid = t >> 6;
    unsigned int v = (t < nb) ? partial[t] : 0u;
    unsigned int orig = v;
    #pragma unroll
    for (int off = 1; off < 64; off <<= 1) {
        unsigned int s = __shfl_up(v, off);
        if (lane >= off) v += s;
    }
    if (lane == 63) wsum[wid] = v;
    __syncthreads();
    unsigned int add = 0;
    for (int i = 0; i < wid; ++i) add += wsum[i];
    if (t < nb) partial[t] = v + add - orig;
}

__global__ __launch_bounds__(256) void pwrite_k(
    unsigned int* __restrict__ data, const unsigned int* __restrict__ partial, int L)
{
    __shared__ unsigned int wsum[4];
    int i = blockIdx.x * 256 + threadIdx.x;
    int lane = threadIdx.x & 63, wid = threadIdx.x >> 6;
    unsigned int v = (i < L) ? data[i] : 0u;
    unsigned int orig = v;
    #pragma unroll
    for (int off = 1; off < 64; off <<= 1) {
        unsigned int s = __shfl_up(v, off);
        if (lane >= off) v += s;
    }
    if (lane == 63) wsum[wid] = v;
    __syncthreads();
    unsigned int add = partial[blockIdx.x];
    for (int w = 0; w < wid; ++w) add += wsum[w];
    if (i < L) data[i] = add + v - orig;
}

// ---------- place into bucket-grouped staging (LDS cursors) ----------

__global__ __launch_bounds__(256) void place_k(
    const int* __restrict__ esrc, const int* __restrict__ edst,
    const float* __restrict__ attr, const unsigned int* __restrict__ off,
    int2* __restrict__ staging, int E, int chunk, int NBUCKET)
{
    __shared__ unsigned int cur[NB_MAX];
    int t = threadIdx.x;
    for (int b = t; b < NBUCKET; b += 256)
        cur[b] = off[(size_t)b * PART_B + blockIdx.x];
    __syncthreads();
    int e0 = blockIdx.x * chunk;
    int e1 = e0 + chunk; if (e1 > E) e1 = E;
    for (int e = e0 + t; e < e1; e += 256) {
        int d = edst[e];
        unsigned int pos = atomicAdd(&cur[d >> 7], 1u);
        staging[pos] = make_int2(esrc[e] | ((d & 127) << 17), __float_as_int(attr[e]));
    }
}

// ---------- per-bucket sort by (node, quartile); emits slotptr ----------

__global__ __launch_bounds__(256) void binsort_k(
    const int2* __restrict__ staging, const unsigned int* __restrict__ off,
    unsigned int* __restrict__ slotptr, int2* __restrict__ packed,
    int N, int E, int NBUCKET)
{
    __shared__ unsigned int nh[512];
    __shared__ unsigned int curb[512];
    __shared__ unsigned int wsum[4];
    int bkt = blockIdx.x, t = threadIdx.x;
    int node0 = bkt << 7;
    unsigned int start = off[(size_t)bkt * PART_B];
    unsigned int end = (bkt + 1 < NBUCKET) ? off[(size_t)(bkt + 1) * PART_B]
                                           : (unsigned int)E;
    nh[t] = 0u; nh[t + 256] = 0u;
    __syncthreads();
    for (unsigned int i = start + t; i < end; i += 256) {
        int2 r = staging[i];
        float p = __int_as_float(r.y);
        int q = (int)(p * 4.0f); q = q > 3 ? 3 : q;
        atomicAdd(&nh[(((r.x >> 17) & 127) << 2) | q], 1u);
    }
    __syncthreads();
    int lane = t & 63, wid = t >> 6;
    unsigned int v0 = nh[2 * t], v1 = nh[2 * t + 1];
    unsigned int pair = v0 + v1, inc = pair;
    #pragma unroll
    for (int o = 1; o < 64; o <<= 1) {
        unsigned int s = __shfl_up(inc, o);
        if (lane >= o) inc += s;
    }
    if (lane == 63) wsum[wid] = inc;
    __syncthreads();
    unsigned int wo = 0;
    for (int i = 0; i < wid; ++i) wo += wsum[i];
    unsigned int excl = wo + inc - pair;
    unsigned int b0 = start + excl, b1 = b0 + v0;
    curb[2 * t] = b0; curb[2 * t + 1] = b1;
    int j0 = 2 * t, j1 = 2 * t + 1;
    if (node0 + (j0 >> 2) < N) slotptr[(size_t)node0 * 4 + j0] = b0;
    if (node0 + (j1 >> 2) < N) slotptr[(size_t)node0 * 4 + j1] = b1;
    if (bkt == NBUCKET - 1 && t == 0) slotptr[(size_t)N * 4] = (unsigned int)E;
    __syncthreads();
    for (unsigned int i = start + t; i < end; i += 256) {
        int2 r = staging[i];
        float p = __int_as_float(r.y);
        int q = (int)(p * 4.0f); q = q > 3 ? 3 : q;
        unsigned int pos = atomicAdd(&curb[(((r.x >> 17) & 127) << 2) | q], 1u);
        packed[pos] = make_int2(r.x & 0x1FFFF, r.y);
    }
}

// ---------- gather: phase-paired dual-stream quartile loop ----------
// wave = node; lane = (edge-slot sub 0..3) x (16 half4 cols).
// phase 0: buckets {0,2} concurrently; phase 1: buckets {1,3}.
// Slots compile-time; 2 row-loads in flight per iteration; fp32 acc.

template<int K>
__global__ __launch_bounds__(256) void gather_k(
    const _Float16* __restrict__ xin,
    const int2* __restrict__ packed,
    const unsigned int* __restrict__ slotptr,
    _Float16* __restrict__ agg, int N, int E)
{
    int n = blockIdx.x * 4 + (threadIdx.x >> 6);
    int lane = threadIdx.x & 63;
    if (n >= N) return;
    int sub = lane >> 4;
    int col = (lane & 15) << 2;
    unsigned int sp[5];
    #pragma unroll
    for (int q = 0; q < 5; ++q) sp[q] = slotptr[(size_t)n * 4 + q];
    float acc[K][4];
    #pragma unroll
    for (int k = 0; k < K; ++k)
        #pragma unroll
        for (int j = 0; j < 4; ++j) acc[k][j] = 0.f;

    #pragma unroll
    for (int ph = 0; ph < 2; ++ph) {
        const int qA = ph, qB = ph + 2;
        const int kA = (K == 5) ? qA : (qA >> 1);
        const int kB = (K == 5) ? qB : (qB >> 1);
        unsigned int iA = sp[qA], endA = sp[qA + 1];
        unsigned int iB = sp[qB], endB = sp[qB + 1];
        while (iA < endA || iB < endB) {
            unsigned int eA = iA + (unsigned int)sub;
            unsigned int eB = iB + (unsigned int)sub;
            bool vA = eA < endA, vB = eB < endB;
            int2 peA = packed[vA ? eA : 0u];
            int2 peB = packed[vB ? eB : 0u];
            half4v hvA = *(const half4v*)(xin + (size_t)peA.x * D_FEAT + col);
            half4v hvB = *(const half4v*)(xin + (size_t)peB.x * D_FEAT + col);
            float fA = __int_as_float(peA.y) * 4.0f;
            float fB = __int_as_float(peB.y) * 4.0f;
            float frA = (K == 5) ? (fA - (float)qA) : (fA * 0.5f - (float)kA);
            float frB = (K == 5) ? (fB - (float)qB) : (fB * 0.5f - (float)kB);
            float w1A = vA ? frA : 0.f, w0A = vA ? 1.f - frA : 0.f;
            float w1B = vB ? frB : 0.f, w0B = vB ? 1.f - frB : 0.f;
            #pragma unroll
            for (int j = 0; j < 4; ++j) {
                float xvA = (float)hvA[j];
                acc[kA][j]     = fmaf(xvA, w0A, acc[kA][j]);
                acc[kA + 1][j] = fmaf(xvA, w1A, acc[kA + 1][j]);
            }
            #pragma unroll
            for (int j = 0; j < 4; ++j) {
                float xvB = (float)hvB[j];
                acc[kB][j]     = fmaf(xvB, w0B, acc[kB][j]);
                acc[kB + 1][j] = fmaf(xvB, w1B, acc[kB + 1][j]);
            }
            iA += 4; iB += 4;
        }
    }

    float inv = 1.f / fmaxf((float)(sp[4] - sp[0]), 1.f);
    #pragma unroll
    for (int k = 0; k < K; ++k) {
        float a[4];
        #pragma unroll
        for (int j = 0; j < 4; ++j) {
            a[j] = acc[k][j];
            a[j] += __shfl_xor(a[j], 16);
            a[j] += __shfl_xor(a[j], 32);
        }
        if (sub == 0) {
            half4v o = { (_Float16)(a[0] * inv), (_Float16)(a[1] * inv),
                         (_Float16)(a[2] * inv), (_Float16)(a[3] * inv) };
            *(half4v*)(agg + ((size_t)n * K + k) * D_FEAT + col) = o;
        }
    }
}

// ---------- MFMA GEMM (+ optional fused MLP head) ----------
// 128x64 tile / 256 threads; wave w = rows w*32..w*32+31.
// Frags (R4/R5-verified): A[m=lane&15][k=q*8+j], B from Wt[n=lane&15][k],
// C/D col=lane&15, row=q*4+reg.
// DO_MLP: h2 tile -> LDS (per-wave rows), 2 more MFMA stages, fp32 out.

template<int K, bool DO_MLP>
__global__ __launch_bounds__(256) void gemm_mfma(
    const _Float16* __restrict__ A,
    const _Float16* __restrict__ X,
    const _Float16* __restrict__ Wt,
    const float* __restrict__ bias,
    const _Float16* __restrict__ Wm1t,
    const float* __restrict__ bm1,
    const _Float16* __restrict__ Wm2t,
    const float* __restrict__ bm2,
    _Float16* __restrict__ outh,
    float* __restrict__ outf,
    int N)
{
    constexpr int lenA = K * 64;
    constexpr int Kd = lenA + D_FEAT;
    constexpr int SMEM_H = DO_MLP ? (128 * 72 * 2) : (128 * AS_STRIDE + 64 * AS_STRIDE);
    __shared__ _Float16 smem[SMEM_H];
    _Float16* As = smem;
    _Float16* Bs = smem + 128 * AS_STRIDE;

    int t = threadIdx.x;
    int row0 = blockIdx.x * 128;
    int w = t >> 6, lane = t & 63;
    int m16 = lane & 15, q = lane >> 4;

    f32x4 acc[2][4];
    #pragma unroll
    for (int rf = 0; rf < 2; ++rf)
        #pragma unroll
        for (int c = 0; c < 4; ++c) acc[rf][c] = (f32x4){0.f, 0.f, 0.f, 0.f};

    int srow = t >> 1;
    int skh  = (t & 1) * 16;
    int bn   = t >> 2;
    int bkq  = (t & 3) * 8;

    int grow = row0 + srow; if (grow >= N) grow = N - 1;
    const _Float16* arowA = A + (size_t)grow * lenA;
    const _Float16* arowX = X + (size_t)grow * D_FEAT;

    for (int kk = 0; kk < Kd; kk += 32) {
        const _Float16* src = (kk < lenA) ? (arowA + kk + skh)
                                          : (arowX + (kk - lenA) + skh);
        half8v a0 = *(const half8v*)(src);
        half8v a1 = *(const half8v*)(src + 8);
        half8v b0 = *(const half8v*)(Wt + (size_t)bn * Kd + kk + bkq);
        __syncthreads();
        *(half8v*)(&As[srow * AS_STRIDE + skh]) = a0;
        *(half8v*)(&As[srow * AS_STRIDE + skh + 8]) = a1;
        *(half8v*)(&Bs[bn * AS_STRIDE + bkq]) = b0;
        __syncthreads();
        half8v af0 = *(const half8v*)(&As[(w * 32 + m16) * AS_STRIDE + q * 8]);
        half8v af1 = *(const half8v*)(&As[(w * 32 + 16 + m16) * AS_STRIDE + q * 8]);
        #pragma unroll
        for (int c = 0; c < 4; ++c) {
            half8v bf = *(const half8v*)(&Bs[(c * 16 + m16) * AS_STRIDE + q * 8]);
            acc[0][c] = __builtin_amdgcn_mfma_f32_16x16x32_f16(af0, bf, acc[0][c], 0, 0, 0);
            acc[1][c] = __builtin_amdgcn_mfma_f32_16x16x32_f16(af1, bf, acc[1][c], 0, 0, 0);
        }
    }

    if (!DO_MLP) {
        #pragma unroll
        for (int rf = 0; rf < 2; ++rf)
            #pragma unroll
            for (int c = 0; c < 4; ++c) {
                int colg = c * 16 + m16;
                float bb = bias[colg];
                #pragma unroll
                for (int r = 0; r < 4; ++r) {
                    int rowg = row0 + w * 32 + rf * 16 + q * 4 + r;
                    if (rowg < N)
                        outh[(size_t)rowg * D_FEAT + colg] = (_Float16)elu_f(acc[rf][c][r] + bb);
                }
            }
        return;
    }

    // fused MLP head: per-wave self-contained rows (w*32..w*32+31)
    _Float16* Hs  = smem;               // [128][72]
    _Float16* Hs2 = smem + 128 * 72;    // [128][72]
    __syncthreads();                    // done with As/Bs
    #pragma unroll
    for (int rf = 0; rf < 2; ++rf)
        #pragma unroll
        for (int c = 0; c < 4; ++c) {
            int colg = c * 16 + m16;
            float bb = bias[colg];
            #pragma unroll
            for (int r = 0; r < 4; ++r)
                Hs[(w * 32 + rf * 16 + q * 4 + r) * 72 + colg] =
                    (_Float16)elu_f(acc[rf][c][r] + bb);
        }

    f32x4 acc3[2][4];
    #pragma unroll
    for (int rf = 0; rf < 2; ++rf)
        #pragma unroll
        for (int c = 0; c < 4; ++c) acc3[rf][c] = (f32x4){0.f, 0.f, 0.f, 0.f};
    #pragma unroll
    for (int kk = 0; kk < 64; kk += 32) {
        half8v af0 = *(const half8v*)(&Hs[(w * 32 + m16) * 72 + kk + q * 8]);
        half8v af1 = *(const half8v*)(&Hs[(w * 32 + 16 + m16) * 72 + kk + q * 8]);
        #pragma unroll
        for (int c = 0; c < 4; ++c) {
            half8v bf = *(const half8v*)(Wm1t + (size_t)(c * 16 + m16) * 64 + kk + q * 8);
            acc3[0][c] = __builtin_amdgcn_mfma_f32_16x16x32_f16(af0, bf, acc3[0][c], 0, 0, 0);
            acc3[1][c] = __builtin_amdgcn_mfma_f32_16x16x32_f16(af1, bf, acc3[1][c], 0, 0, 0);
        }
    }
    #pragma unroll
    for (int rf = 0; rf < 2; ++rf)
        #pragma unroll
        for (int c = 0; c < 4; ++c) {
            int colg = c * 16 + m16;
            float bb = bm1[colg];
            #pragma unroll
            for (int r = 0; r < 4; ++r)
                Hs2[(w * 32 + rf * 16 + q * 4 + r) * 72 + colg] =
                    (_Float16)fmaxf(acc3[rf][c][r] + bb, 0.f);
        }

    f32x4 acc4[2];
    acc4[0] = (f32x4){0.f, 0.f, 0.f, 0.f};
    acc4[1] = (f32x4){0.f, 0.f, 0.f, 0.f};
    #pragma unroll
    for (int kk = 0; kk < 64; kk += 32) {
        half8v af0 = *(const half8v*)(&Hs2[(w * 32 + m16) * 72 + kk + q * 8]);
        half8v af1 = *(const half8v*)(&Hs2[(w * 32 + 16 + m16) * 72 + kk + q * 8]);
        half8v bf = *(const half8v*)(Wm2t + (size_t)m16 * 64 + kk + q * 8);
        acc4[0] = __builtin_amdgcn_mfma_f32_16x16x32_f16(af0, bf, acc4[0], 0, 0, 0);
        acc4[1] = __builtin_amdgcn_mfma_f32_16x16x32_f16(af1, bf, acc4[1], 0, 0, 0);
    }
    float bb2 = bm2[m16];
    #pragma unroll
    for (int rf = 0; rf < 2; ++rf)
        #pragma unroll
        for (int r = 0; r < 4; ++r) {
            int rowg = row0 + w * 32 + rf * 16 + q * 4 + r;
            if (rowg < N)
                outf[(size_t)rowg * 16 + m16] = fmaxf(acc4[rf][r] + bb2, 0.f);
        }
}

extern "C" void kernel_launch(void* const* d_in, const int* in_sizes, int n_in,
                              void* d_out, int out_size, void* d_ws, size_t ws_size,
                              hipStream_t stream)
{
    const float* x     = (const float*)d_in[0];
    const int*   eidx  = (const int*)d_in[1];
    const float* attr  = (const float*)d_in[2];
    const float* W1    = (const float*)d_in[3];
    const float* root1 = (const float*)d_in[4];
    const float* b1    = (const float*)d_in[5];
    const float* W2    = (const float*)d_in[6];
    const float* root2 = (const float*)d_in[7];
    const float* b2    = (const float*)d_in[8];
    const float* Wm1   = (const float*)d_in[9];
    const float* bm1   = (const float*)d_in[10];
    const float* Wm2   = (const float*)d_in[11];
    const float* bm2   = (const float*)d_in[12];
    float* out = (float*)d_out;

    int N = in_sizes[0] / D_FEAT;
    int E = in_sizes[1] / 2;
    const int* esrc = eidx;
    const int* edst = eidx + E;
    int NBUCKET = (N + 127) >> 7;
    int chunk = (E + PART_B - 1) / PART_B;
    int L = NBUCKET * PART_B;
    int nbL = (L + 255) / 256;
    int total8 = N * D_FEAT / 8;
    int cvtB = (total8 + 255) / 256;
    int wElems = 64 * 256 + 64 * 384 + 64 * 64 + 16 * 64;
    int wB = (wElems + 255) / 256;

    _Float16* agg = (_Float16*)d_ws;
    _Float16* xh  = agg + (size_t)N * 5 * D_FEAT;
    _Float16* h   = xh + (size_t)N * D_FEAT;
    int2* packed  = (int2*)(h + (size_t)N * D_FEAT);
    int2* staging = packed + E;
    _Float16* Wt1 = (_Float16*)(staging + E);
    _Float16* Wt2 = Wt1 + 64 * 256;
    _Float16* Wm1t = Wt2 + 64 * 384;
    _Float16* Wm2t = Wm1t + 64 * 64;
    unsigned int* counts  = (unsigned int*)(Wm2t + 16 * 64);
    unsigned int* partial = counts + L;
    unsigned int* slotptr = partial + 512;

    dim3 blk(256);
    dim3 grid_w((N + 3) / 4);
    dim3 grid_g128((N + 127) / 128);

    prep_k<<<dim3(cvtB + PART_B + wB), blk, 0, stream>>>(
        x, edst, W1, root1, W2, root2, Wm1, Wm2,
        xh, counts, Wt1, Wt2, Wm1t, Wm2t, E, chunk, NBUCKET, total8, cvtB);

    psum_k<<<dim3(nbL), blk, 0, stream>>>(counts, partial, L);
    pscan_k<<<1, 512, 0, stream>>>(partial, nbL);
    pwrite_k<<<dim3(nbL), blk, 0, stream>>>(counts, partial, L);
    place_k<<<dim3(PART_B), blk, 0, stream>>>(esrc, edst, attr, counts, staging, E, chunk, NBUCKET);
    binsort_k<<<dim3(NBUCKET), blk, 0, stream>>>(staging, counts, slotptr, packed, N, E, NBUCKET);

    // conv1: K=3
    gather_k<3><<<grid_w, blk, 0, stream>>>(xh, packed, slotptr, agg, N, E);
    gemm_mfma<3, false><<<grid_g128, blk, 0, stream>>>(
        agg, xh, Wt1, b1, nullptr, nullptr, nullptr, nullptr, h, nullptr, N);

    // conv2: K=5 + fused MLP head
    gather_k<5><<<grid_w, blk, 0, stream>>>(h, packed, slotptr, agg, N, E);
    gemm_mfma<5, true><<<grid_g128, blk, 0, stream>>>(
        agg, h, Wt2, b2, Wm1t, bm1, Wm2t, bm2, nullptr, out, N);
}

// Round 9
// 334.098 us; speedup vs baseline: 1.2329x; 1.0003x over previous
//
#include <hip/hip_runtime.h>
#include <cstdint>
#include <cstddef>

// SplineNet: 2x SplineConv (K=3, K=5) + ELU, MLP head. N=100K, E=1.6M, D=64, C=16.
//
// R9: gather inner math + reduction switched to packed fp16 (v_pk_fma_f16):
//   - loop: half4v acc, weights cvt to fp16 once, broadcast; no per-element cvt
//   - epilogue: cross-sub shuffle reduce in packed fp16 (int2 bitcast), 1/deg
//     applied as pk_mul. ~2x fewer VALU instrs in both loop and epilogue.
// Rest unchanged from R8 (dual-stream quartile gather, quartile binsort,
// MFMA GEMMs, MLP fused into gemm<5>, atomic-free partition-sort CSR).
//
// ws: agg[N*320 h] 64MB | xh[N*64 h] | h[N*64 h] | packed[E int2] |
//     staging[E int2] | Wt1 | Wt2 | Wm1t | Wm2t | counts | partial |
//     slotptr[N*4+1]  ~= 118 MB.

#define D_FEAT 64
#define AS_STRIDE 40
#define NB_MAX 1024
#define PART_B 128

typedef _Float16 half8v __attribute__((ext_vector_type(8)));
typedef _Float16 half4v __attribute__((ext_vector_type(4)));
typedef float f32x4 __attribute__((ext_vector_type(4)));

__device__ __forceinline__ float elu_f(float x) {
    return x > 0.f ? x : expm1f(x);
}

// ---------- merged prep: x->fp16 | dst-bucket count | W transposes ----------

__global__ __launch_bounds__(256) void prep_k(
    const float* __restrict__ x, const int* __restrict__ edst,
    const float* __restrict__ W1, const float* __restrict__ root1,
    const float* __restrict__ W2, const float* __restrict__ root2,
    const float* __restrict__ Wm1, const float* __restrict__ Wm2,
    _Float16* __restrict__ xh, unsigned int* __restrict__ counts,
    _Float16* __restrict__ Wt1, _Float16* __restrict__ Wt2,
    _Float16* __restrict__ Wm1t, _Float16* __restrict__ Wm2t,
    int E, int chunk, int NBUCKET, int total8, int cvtB)
{
    __shared__ unsigned int hist[NB_MAX];
    int b = blockIdx.x, t = threadIdx.x;
    if (b < cvtB) {
        int i = b * 256 + t;
        if (i < total8) {
            const float4* src = (const float4*)(x + (size_t)i * 8);
            float4 v0 = src[0], v1 = src[1];
            half8v hv = { (_Float16)v0.x, (_Float16)v0.y, (_Float16)v0.z, (_Float16)v0.w,
                          (_Float16)v1.x, (_Float16)v1.y, (_Float16)v1.z, (_Float16)v1.w };
            ((half8v*)xh)[i] = hv;
        }
        return;
    }
    if (b < cvtB + PART_B) {
        int bb = b - cvtB;
        for (int i = t; i < NBUCKET; i += 256) hist[i] = 0u;
        __syncthreads();
        int e0 = bb * chunk;
        int e1 = e0 + chunk; if (e1 > E) e1 = E;
        for (int e = e0 + t; e < e1; e += 256)
            atomicAdd(&hist[edst[e] >> 7], 1u);
        __syncthreads();
        for (int i = t; i < NBUCKET; i += 256)
            counts[(size_t)i * PART_B + bb] = hist[i];
        return;
    }
    int i = (b - cvtB - PART_B) * 256 + t;
    if (i < 64 * 256) {
        int n = i >> 8, k = i & 255;
        float v = (k < 192) ? W1[k * 64 + n] : root1[(k - 192) * 64 + n];
        Wt1[n * 256 + k] = (_Float16)v;
    } else if (i < 64 * 256 + 64 * 384) {
        int j = i - 64 * 256;
        int n = j / 384, k = j % 384;
        float v = (k < 320) ? W2[k * 64 + n] : root2[(k - 320) * 64 + n];
        Wt2[n * 384 + k] = (_Float16)v;
    } else if (i < 64 * 256 + 64 * 384 + 64 * 64) {
        int j = i - 64 * 256 - 64 * 384;
        int n = j >> 6, k = j & 63;
        Wm1t[n * 64 + k] = (_Float16)Wm1[k * 64 + n];
    } else if (i < 64 * 256 + 64 * 384 + 64 * 64 + 16 * 64) {
        int j = i - 64 * 256 - 64 * 384 - 64 * 64;
        int n = j >> 6, k = j & 63;
        Wm2t[n * 64 + k] = (_Float16)Wm2[k * 16 + n];
    }
}

// ---------- flat multi-block exclusive scan over counts[L] ----------

__global__ __launch_bounds__(256) void psum_k(
    const unsigned int* __restrict__ data, unsigned int* __restrict__ partial, int L)
{
    __shared__ unsigned int wsum[4];
    int i = blockIdx.x * 256 + threadIdx.x;
    int lane = threadIdx.x & 63, wid = threadIdx.x >> 6;
    unsigned int v = (i < L) ? data[i] : 0u;
    #pragma unroll
    for (int off = 32; off; off >>= 1) v += __shfl_xor(v, off);
    if (lane == 0) wsum[wid] = v;
    __syncthreads();
    if (threadIdx.x == 0)
        partial[blockIdx.x] = wsum[0] + wsum[1] + wsum[2] + wsum[3];
}

__global__ __launch_bounds__(512) void pscan_k(
    unsigned int* __restrict__ partial, int nb)
{
    __shared__ unsigned int wsum[8];
    int t = threadIdx.x, lane = t & 63, wid = t >> 6;
    unsigned int v = (t < nb) ? partial[t] : 0u;
    unsigned int orig = v;
    #pragma unroll
    for (int off = 1; off < 64; off <<= 1) {
        unsigned int s = __shfl_up(v, off);
        if (lane >= off) v += s;
    }
    if (lane == 63) wsum[wid] = v;
    __syncthreads();
    unsigned int add = 0;
    for (int i = 0; i < wid; ++i) add += wsum[i];
    if (t < nb) partial[t] = v + add - orig;
}

__global__ __launch_bounds__(256) void pwrite_k(
    unsigned int* __restrict__ data, const unsigned int* __restrict__ partial, int L)
{
    __shared__ unsigned int wsum[4];
    int i = blockIdx.x * 256 + threadIdx.x;
    int lane = threadIdx.x & 63, wid = threadIdx.x >> 6;
    unsigned int v = (i < L) ? data[i] : 0u;
    unsigned int orig = v;
    #pragma unroll
    for (int off = 1; off < 64; off <<= 1) {
        unsigned int s = __shfl_up(v, off);
        if (lane >= off) v += s;
    }
    if (lane == 63) wsum[wid] = v;
    __syncthreads();
    unsigned int add = partial[blockIdx.x];
    for (int w = 0; w < wid; ++w) add += wsum[w];
    if (i < L) data[i] = add + v - orig;
}

// ---------- place into bucket-grouped staging (LDS cursors) ----------

__global__ __launch_bounds__(256) void place_k(
    const int* __restrict__ esrc, const int* __restrict__ edst,
    const float* __restrict__ attr, const unsigned int* __restrict__ off,
    int2* __restrict__ staging, int E, int chunk, int NBUCKET)
{
    __shared__ unsigned int cur[NB_MAX];
    int t = threadIdx.x;
    for (int b = t; b < NBUCKET; b += 256)
        cur[b] = off[(size_t)b * PART_B + blockIdx.x];
    __syncthreads();
    int e0 = blockIdx.x * chunk;
    int e1 = e0 + chunk; if (e1 > E) e1 = E;
    for (int e = e0 + t; e < e1; e += 256) {
        int d = edst[e];
        unsigned int pos = atomicAdd(&cur[d >> 7], 1u);
        staging[pos] = make_int2(esrc[e] | ((d & 127) << 17), __float_as_int(attr[e]));
    }
}

// ---------- per-bucket sort by (node, quartile); emits slotptr ----------

__global__ __launch_bounds__(256) void binsort_k(
    const int2* __restrict__ staging, const unsigned int* __restrict__ off,
    unsigned int* __restrict__ slotptr, int2* __restrict__ packed,
    int N, int E, int NBUCKET)
{
    __shared__ unsigned int nh[512];
    __shared__ unsigned int curb[512];
    __shared__ unsigned int wsum[4];
    int bkt = blockIdx.x, t = threadIdx.x;
    int node0 = bkt << 7;
    unsigned int start = off[(size_t)bkt * PART_B];
    unsigned int end = (bkt + 1 < NBUCKET) ? off[(size_t)(bkt + 1) * PART_B]
                                           : (unsigned int)E;
    nh[t] = 0u; nh[t + 256] = 0u;
    __syncthreads();
    for (unsigned int i = start + t; i < end; i += 256) {
        int2 r = staging[i];
        float p = __int_as_float(r.y);
        int q = (int)(p * 4.0f); q = q > 3 ? 3 : q;
        atomicAdd(&nh[(((r.x >> 17) & 127) << 2) | q], 1u);
    }
    __syncthreads();
    int lane = t & 63, wid = t >> 6;
    unsigned int v0 = nh[2 * t], v1 = nh[2 * t + 1];
    unsigned int pair = v0 + v1, inc = pair;
    #pragma unroll
    for (int o = 1; o < 64; o <<= 1) {
        unsigned int s = __shfl_up(inc, o);
        if (lane >= o) inc += s;
    }
    if (lane == 63) wsum[wid] = inc;
    __syncthreads();
    unsigned int wo = 0;
    for (int i = 0; i < wid; ++i) wo += wsum[i];
    unsigned int excl = wo + inc - pair;
    unsigned int b0 = start + excl, b1 = b0 + v0;
    curb[2 * t] = b0; curb[2 * t + 1] = b1;
    int j0 = 2 * t, j1 = 2 * t + 1;
    if (node0 + (j0 >> 2) < N) slotptr[(size_t)node0 * 4 + j0] = b0;
    if (node0 + (j1 >> 2) < N) slotptr[(size_t)node0 * 4 + j1] = b1;
    if (bkt == NBUCKET - 1 && t == 0) slotptr[(size_t)N * 4] = (unsigned int)E;
    __syncthreads();
    for (unsigned int i = start + t; i < end; i += 256) {
        int2 r = staging[i];
        float p = __int_as_float(r.y);
        int q = (int)(p * 4.0f); q = q > 3 ? 3 : q;
        unsigned int pos = atomicAdd(&curb[(((r.x >> 17) & 127) << 2) | q], 1u);
        packed[pos] = make_int2(r.x & 0x1FFFF, r.y);
    }
}

// ---------- gather: dual-stream quartile loop, packed-fp16 math ----------
// wave = node; lane = (edge-slot sub 0..3) x (16 half4 cols).
// phase 0: buckets {0,2}; phase 1: {1,3}. Compile-time slots; half4v acc
// (v_pk_fma_f16); cross-sub reduce in packed fp16 via int2-bitcast shuffles.

template<int K>
__global__ __launch_bounds__(256) void gather_k(
    const _Float16* __restrict__ xin,
    const int2* __restrict__ packed,
    const unsigned int* __restrict__ slotptr,
    _Float16* __restrict__ agg, int N, int E)
{
    int n = blockIdx.x * 4 + (threadIdx.x >> 6);
    int lane = threadIdx.x & 63;
    if (n >= N) return;
    int sub = lane >> 4;
    int col = (lane & 15) << 2;
    unsigned int sp[5];
    #pragma unroll
    for (int q = 0; q < 5; ++q) sp[q] = slotptr[(size_t)n * 4 + q];
    half4v acc[K];
    #pragma unroll
    for (int k = 0; k < K; ++k) acc[k] = (half4v){0, 0, 0, 0};

    #pragma unroll
    for (int ph = 0; ph < 2; ++ph) {
        const int qA = ph, qB = ph + 2;
        const int kA = (K == 5) ? qA : (qA >> 1);
        const int kB = (K == 5) ? qB : (qB >> 1);
        unsigned int iA = sp[qA], endA = sp[qA + 1];
        unsigned int iB = sp[qB], endB = sp[qB + 1];
        while (iA < endA || iB < endB) {
            unsigned int eA = iA + (unsigned int)sub;
            unsigned int eB = iB + (unsigned int)sub;
            bool vA = eA < endA, vB = eB < endB;
            int2 peA = packed[vA ? eA : 0u];
            int2 peB = packed[vB ? eB : 0u];
            half4v hvA = *(const half4v*)(xin + (size_t)peA.x * D_FEAT + col);
            half4v hvB = *(const half4v*)(xin + (size_t)peB.x * D_FEAT + col);
            float fA = __int_as_float(peA.y) * 4.0f;
            float fB = __int_as_float(peB.y) * 4.0f;
            float frA = (K == 5) ? (fA - (float)qA) : (fA * 0.5f - (float)kA);
            float frB = (K == 5) ? (fB - (float)qB) : (fB * 0.5f - (float)kB);
            float w1A = vA ? frA : 0.f, w0A = vA ? 1.f - frA : 0.f;
            float w1B = vB ? frB : 0.f, w0B = vB ? 1.f - frB : 0.f;
            _Float16 h0A = (_Float16)w0A, h1A = (_Float16)w1A;
            _Float16 h0B = (_Float16)w0B, h1B = (_Float16)w1B;
            half4v w0Av = {h0A, h0A, h0A, h0A}, w1Av = {h1A, h1A, h1A, h1A};
            half4v w0Bv = {h0B, h0B, h0B, h0B}, w1Bv = {h1B, h1B, h1B, h1B};
            acc[kA]     += hvA * w0Av;
            acc[kA + 1] += hvA * w1Av;
            acc[kB]     += hvB * w0Bv;
            acc[kB + 1] += hvB * w1Bv;
            iA += 4; iB += 4;
        }
    }

    float inv = 1.f / fmaxf((float)(sp[4] - sp[0]), 1.f);
    _Float16 invh = (_Float16)inv;
    half4v invv = {invh, invh, invh, invh};
    #pragma unroll
    for (int k = 0; k < K; ++k) {
        union { half4v h; int2 i; } u, s;
        u.h = acc[k];
        s.i.x = __shfl_xor(u.i.x, 16);
        s.i.y = __shfl_xor(u.i.y, 16);
        u.h += s.h;
        s.i.x = __shfl_xor(u.i.x, 32);
        s.i.y = __shfl_xor(u.i.y, 32);
        u.h += s.h;
        u.h *= invv;
        if (sub == 0)
            *(half4v*)(agg + ((size_t)n * K + k) * D_FEAT + col) = u.h;
    }
}

// ---------- MFMA GEMM (+ optional fused MLP head) ----------
// 128x64 tile / 256 threads; wave w = rows w*32..w*32+31.
// Frags (R4/R5-verified): A[m=lane&15][k=q*8+j], B from Wt[n=lane&15][k],
// C/D col=lane&15, row=q*4+reg.
// DO_MLP: h2 tile -> LDS (per-wave rows), 2 more MFMA stages, fp32 out.

template<int K, bool DO_MLP>
__global__ __launch_bounds__(256) void gemm_mfma(
    const _Float16* __restrict__ A,
    const _Float16* __restrict__ X,
    const _Float16* __restrict__ Wt,
    const float* __restrict__ bias,
    const _Float16* __restrict__ Wm1t,
    const float* __restrict__ bm1,
    const _Float16* __restrict__ Wm2t,
    const float* __restrict__ bm2,
    _Float16* __restrict__ outh,
    float* __restrict__ outf,
    int N)
{
    constexpr int lenA = K * 64;
    constexpr int Kd = lenA + D_FEAT;
    constexpr int SMEM_H = DO_MLP ? (128 * 72 * 2) : (128 * AS_STRIDE + 64 * AS_STRIDE);
    __shared__ _Float16 smem[SMEM_H];
    _Float16* As = smem;
    _Float16* Bs = smem + 128 * AS_STRIDE;

    int t = threadIdx.x;
    int row0 = blockIdx.x * 128;
    int w = t >> 6, lane = t & 63;
    int m16 = lane & 15, q = lane >> 4;

    f32x4 acc[2][4];
    #pragma unroll
    for (int rf = 0; rf < 2; ++rf)
        #pragma unroll
        for (int c = 0; c < 4; ++c) acc[rf][c] = (f32x4){0.f, 0.f, 0.f, 0.f};

    int srow = t >> 1;
    int skh  = (t & 1) * 16;
    int bn   = t >> 2;
    int bkq  = (t & 3) * 8;

    int grow = row0 + srow; if (grow >= N) grow = N - 1;
    const _Float16* arowA = A + (size_t)grow * lenA;
    const _Float16* arowX = X + (size_t)grow * D_FEAT;

    for (int kk = 0; kk < Kd; kk += 32) {
        const _Float16* src = (kk < lenA) ? (arowA + kk + skh)
                                          : (arowX + (kk - lenA) + skh);
        half8v a0 = *(const half8v*)(src);
        half8v a1 = *(const half8v*)(src + 8);
        half8v b0 = *(const half8v*)(Wt + (size_t)bn * Kd + kk + bkq);
        __syncthreads();
        *(half8v*)(&As[srow * AS_STRIDE + skh]) = a0;
        *(half8v*)(&As[srow * AS_STRIDE + skh + 8]) = a1;
        *(half8v*)(&Bs[bn * AS_STRIDE + bkq]) = b0;
        __syncthreads();
        half8v af0 = *(const half8v*)(&As[(w * 32 + m16) * AS_STRIDE + q * 8]);
        half8v af1 = *(const half8v*)(&As[(w * 32 + 16 + m16) * AS_STRIDE + q * 8]);
        #pragma unroll
        for (int c = 0; c < 4; ++c) {
            half8v bf = *(const half8v*)(&Bs[(c * 16 + m16) * AS_STRIDE + q * 8]);
            acc[0][c] = __builtin_amdgcn_mfma_f32_16x16x32_f16(af0, bf, acc[0][c], 0, 0, 0);
            acc[1][c] = __builtin_amdgcn_mfma_f32_16x16x32_f16(af1, bf, acc[1][c], 0, 0, 0);
        }
    }

    if (!DO_MLP) {
        #pragma unroll
        for (int rf = 0; rf < 2; ++rf)
            #pragma unroll
            for (int c = 0; c < 4; ++c) {
                int colg = c * 16 + m16;
                float bb = bias[colg];
                #pragma unroll
                for (int r = 0; r < 4; ++r) {
                    int rowg = row0 + w * 32 + rf * 16 + q * 4 + r;
                    if (rowg < N)
                        outh[(size_t)rowg * D_FEAT + colg] = (_Float16)elu_f(acc[rf][c][r] + bb);
                }
            }
        return;
    }

    // fused MLP head: per-wave self-contained rows (w*32..w*32+31)
    _Float16* Hs  = smem;               // [128][72]
    _Float16* Hs2 = smem + 128 * 72;    // [128][72]
    __syncthreads();                    // done with As/Bs
    #pragma unroll
    for (int rf = 0; rf < 2; ++rf)
        #pragma unroll
        for (int c = 0; c < 4; ++c) {
            int colg = c * 16 + m16;
            float bb = bias[colg];
            #pragma unroll
            for (int r = 0; r < 4; ++r)
                Hs[(w * 32 + rf * 16 + q * 4 + r) * 72 + colg] =
                    (_Float16)elu_f(acc[rf][c][r] + bb);
        }

    f32x4 acc3[2][4];
    #pragma unroll
    for (int rf = 0; rf < 2; ++rf)
        #pragma unroll
        for (int c = 0; c < 4; ++c) acc3[rf][c] = (f32x4){0.f, 0.f, 0.f, 0.f};
    #pragma unroll
    for (int kk = 0; kk < 64; kk += 32) {
        half8v af0 = *(const half8v*)(&Hs[(w * 32 + m16) * 72 + kk + q * 8]);
        half8v af1 = *(const half8v*)(&Hs[(w * 32 + 16 + m16) * 72 + kk + q * 8]);
        #pragma unroll
        for (int c = 0; c < 4; ++c) {
            half8v bf = *(const half8v*)(Wm1t + (size_t)(c * 16 + m16) * 64 + kk + q * 8);
            acc3[0][c] = __builtin_amdgcn_mfma_f32_16x16x32_f16(af0, bf, acc3[0][c], 0, 0, 0);
            acc3[1][c] = __builtin_amdgcn_mfma_f32_16x16x32_f16(af1, bf, acc3[1][c], 0, 0, 0);
        }
    }
    #pragma unroll
    for (int rf = 0; rf < 2; ++rf)
        #pragma unroll
        for (int c = 0; c < 4; ++c) {
            int colg = c * 16 + m16;
            float bb = bm1[colg];
            #pragma unroll
            for (int r = 0; r < 4; ++r)
                Hs2[(w * 32 + rf * 16 + q * 4 + r) * 72 + colg] =
                    (_Float16)fmaxf(acc3[rf][c][r] + bb, 0.f);
        }

    f32x4 acc4[2];
    acc4[0] = (f32x4){0.f, 0.f, 0.f, 0.f};
    acc4[1] = (f32x4){0.f, 0.f, 0.f, 0.f};
    #pragma unroll
    for (int kk = 0; kk < 64; kk += 32) {
        half8v af0 = *(const half8v*)(&Hs2[(w * 32 + m16) * 72 + kk + q * 8]);
        half8v af1 = *(const half8v*)(&Hs2[(w * 32 + 16 + m16) * 72 + kk + q * 8]);
        half8v bf = *(const half8v*)(Wm2t + (size_t)m16 * 64 + kk + q * 8);
        acc4[0] = __builtin_amdgcn_mfma_f32_16x16x32_f16(af0, bf, acc4[0], 0, 0, 0);
        acc4[1] = __builtin_amdgcn_mfma_f32_16x16x32_f16(af1, bf, acc4[1], 0, 0, 0);
    }
    float bb2 = bm2[m16];
    #pragma unroll
    for (int rf = 0; rf < 2; ++rf)
        #pragma unroll
        for (int r = 0; r < 4; ++r) {
            int rowg = row0 + w * 32 + rf * 16 + q * 4 + r;
            if (rowg < N)
                outf[(size_t)rowg * 16 + m16] = fmaxf(acc4[rf][r] + bb2, 0.f);
        }
}

extern "C" void kernel_launch(void* const* d_in, const int* in_sizes, int n_in,
                              void* d_out, int out_size, void* d_ws, size_t ws_size,
                              hipStream_t stream)
{
    const float* x     = (const float*)d_in[0];
    const int*   eidx  = (const int*)d_in[1];
    const float* attr  = (const float*)d_in[2];
    const float* W1    = (const float*)d_in[3];
    const float* root1 = (const float*)d_in[4];
    const float* b1    = (const float*)d_in[5];
    const float* W2    = (const float*)d_in[6];
    const float* root2 = (const float*)d_in[7];
    const float* b2    = (const float*)d_in[8];
    const float* Wm1   = (const float*)d_in[9];
    const float* bm1   = (const float*)d_in[10];
    const float* Wm2   = (const float*)d_in[11];
    const float* bm2   = (const float*)d_in[12];
    float* out = (float*)d_out;

    int N = in_sizes[0] / D_FEAT;
    int E = in_sizes[1] / 2;
    const int* esrc = eidx;
    const int* edst = eidx + E;
    int NBUCKET = (N + 127) >> 7;
    int chunk = (E + PART_B - 1) / PART_B;
    int L = NBUCKET * PART_B;
    int nbL = (L + 255) / 256;
    int total8 = N * D_FEAT / 8;
    int cvtB = (total8 + 255) / 256;
    int wElems = 64 * 256 + 64 * 384 + 64 * 64 + 16 * 64;
    int wB = (wElems + 255) / 256;

    _Float16* agg = (_Float16*)d_ws;
    _Float16* xh  = agg + (size_t)N * 5 * D_FEAT;
    _Float16* h   = xh + (size_t)N * D_FEAT;
    int2* packed  = (int2*)(h + (size_t)N * D_FEAT);
    int2* staging = packed + E;
    _Float16* Wt1 = (_Float16*)(staging + E);
    _Float16* Wt2 = Wt1 + 64 * 256;
    _Float16* Wm1t = Wt2 + 64 * 384;
    _Float16* Wm2t = Wm1t + 64 * 64;
    unsigned int* counts  = (unsigned int*)(Wm2t + 16 * 64);
    unsigned int* partial = counts + L;
    unsigned int* slotptr = partial + 512;

    dim3 blk(256);
    dim3 grid_w((N + 3) / 4);
    dim3 grid_g128((N + 127) / 128);

    prep_k<<<dim3(cvtB + PART_B + wB), blk, 0, stream>>>(
        x, edst, W1, root1, W2, root2, Wm1, Wm2,
        xh, counts, Wt1, Wt2, Wm1t, Wm2t, E, chunk, NBUCKET, total8, cvtB);

    psum_k<<<dim3(nbL), blk, 0, stream>>>(counts, partial, L);
    pscan_k<<<1, 512, 0, stream>>>(partial, nbL);
    pwrite_k<<<dim3(nbL), blk, 0, stream>>>(counts, partial, L);
    place_k<<<dim3(PART_B), blk, 0, stream>>>(esrc, edst, attr, counts, staging, E, chunk, NBUCKET);
    binsort_k<<<dim3(NBUCKET), blk, 0, stream>>>(staging, counts, slotptr, packed, N, E, NBUCKET);

    // conv1: K=3
    gather_k<3><<<grid_w, blk, 0, stream>>>(xh, packed, slotptr, agg, N, E);
    gemm_mfma<3, false><<<grid_g128, blk, 0, stream>>>(
        agg, xh, Wt1, b1, nullptr, nullptr, nullptr, nullptr, h, nullptr, N);

    // conv2: K=5 + fused MLP head
    gather_k<5><<<grid_w, blk, 0, stream>>>(h, packed, slotptr, agg, N, E);
    gemm_mfma<5, true><<<grid_g128, blk, 0, stream>>>(
        agg, h, Wt2, b2, Wm1t, bm1, Wm2t, bm2, nullptr, out, N);
}